// Round 1
// 1309.658 us; speedup vs baseline: 1.4274x; 1.4274x over previous
//
#include <hip/hip_runtime.h>

#define VOCAB 28996
#define BB 32
#define SS 512
#define DD 768
#define NCLS 9
#define ROWS (BB*SS)     // 16384
#define IN2 (2*DD)       // 1536
#define G4 (4*DD)        // 3072
#define NB2 (2*G4)       // 6144

typedef __attribute__((ext_vector_type(8))) short short8;
typedef __attribute__((ext_vector_type(4))) short shortx4;
typedef __attribute__((ext_vector_type(4))) float floatx4;
typedef unsigned long long ull;

__device__ __forceinline__ float bf2f(unsigned short u){
  union { unsigned int i; float f; } v; v.i = ((unsigned int)u) << 16; return v.f;
}
__device__ __forceinline__ unsigned short f2bf(float f){
  union { float f; unsigned int i; } v; v.f = f;
  unsigned int r = v.i + 0x7FFFu + ((v.i >> 16) & 1u);
  return (unsigned short)(r >> 16);
}
__device__ __forceinline__ float sigf(float x){ return 1.0f / (1.0f + __expf(-x)); }
__device__ __forceinline__ float tanhfast(float x){
  float y = fminf(fmaxf(x, -15.f), 15.f);
  float e = __expf(2.f * y);
  return 1.f - 2.f / (e + 1.f);
}

__device__ __forceinline__ void gl_lds16(const unsigned short* g, unsigned short* l){
  __builtin_amdgcn_global_load_lds((__attribute__((address_space(1))) void*)(g),
                                   (__attribute__((address_space(3))) void*)(l), 16, 0, 0);
}
// coherent variant: sc0|sc1 (aux bit0 | bit4) -> bypass L1+L2, read memory-side L3.
// Used ONLY for h (cross-block data); lets us drop the per-step whole-L2 invalidation.
__device__ __forceinline__ void gl_lds16_c(const unsigned short* g, unsigned short* l){
  __builtin_amdgcn_global_load_lds((__attribute__((address_space(1))) void*)(g),
                                   (__attribute__((address_space(3))) void*)(l), 16, 0, 17);
}
// write-through store to the coherence point (L3) so sc1 readers on other XCDs see it
__device__ __forceinline__ void store16_sc1(unsigned short* p, short8 v){
  asm volatile("global_store_dwordx4 %0, %1, off sc0 sc1" :: "v"(p), "v"(v) : "memory");
}

// ---- group barrier: relaxed sc1 atomics for arrival/spin. NO acquire fence --
// h freshness now comes from sc1 loads (bypass L2), so whh/xg stay L2-resident. ----
__device__ __forceinline__ void grid_bar(unsigned* bar, int nb)
{
  __syncthreads();
  if (threadIdx.x == 0) {
    unsigned g = __hip_atomic_load(bar + 1, __ATOMIC_RELAXED, __HIP_MEMORY_SCOPE_AGENT);
    unsigned a = __hip_atomic_fetch_add(bar, 1u, __ATOMIC_RELAXED, __HIP_MEMORY_SCOPE_AGENT);
    if (a == (unsigned)(nb - 1)) {
      __hip_atomic_store(bar, 0u, __ATOMIC_RELAXED, __HIP_MEMORY_SCOPE_AGENT);
      __hip_atomic_store(bar + 1, g + 1u, __ATOMIC_RELEASE, __HIP_MEMORY_SCOPE_AGENT);
    } else {
      unsigned cur;
      do {
        __builtin_amdgcn_s_sleep(2);
        cur = __hip_atomic_load(bar + 1, __ATOMIC_RELAXED, __HIP_MEMORY_SCOPE_AGENT);
      } while (cur == g);
    }
  }
  __syncthreads();
}

// ---------------- segment mean ----------------
__global__ void seg_scatter(const int* __restrict__ ids, const float* __restrict__ hidden,
                            float* __restrict__ sums, float* __restrict__ counts)
{
  int r = blockIdx.x;
  int id = ids[r];
  const float* h = hidden + (long)r * DD;
  float* s = sums + (long)id * DD;
  for (int d = threadIdx.x; d < DD; d += 256)
    atomicAdd(&s[d], h[d]);
  if (threadIdx.x == 0) atomicAdd(&counts[id], 1.0f);
}

__global__ void build_x(const int* __restrict__ ids, const float* __restrict__ hidden,
                        const float* __restrict__ sums, const float* __restrict__ counts,
                        unsigned short* __restrict__ x)
{
  int r = blockIdx.x;
  int id = ids[r];
  float inv = 1.0f / fmaxf(counts[id], 1.0f);
  const float* h = hidden + (long)r * DD;
  const float* s = sums + (long)id * DD;
  unsigned short* xr = x + (long)r * IN2;
  for (int d = threadIdx.x; d < DD; d += 256) {
    xr[d]      = f2bf(h[d]);
    xr[DD + d] = f2bf(s[d] * inv);
  }
}

// -------- weight conversion with gate-interleave permutation: row' = u*4+g <- row g*768+u --------
__global__ void conv_w_perm(const float* __restrict__ w, unsigned short* __restrict__ o, int K)
{
  long i = (long)blockIdx.x * 256 + threadIdx.x;
  if (i >= (long)G4 * K) return;
  int row = (int)(i / K); int k = (int)(i - (long)row * K);
  int u = row >> 2, g = row & 3;
  o[i] = f2bf(w[((long)(g * DD + u)) * K + k]);
}

__global__ void conv_bias_perm(const float* __restrict__ bif, const float* __restrict__ bhf,
                               const float* __restrict__ bib, const float* __restrict__ bhb,
                               float* __restrict__ o)
{
  int n = blockIdx.x * 256 + threadIdx.x;
  if (n >= NB2) return;
  int d = n / G4, rr = n - d * G4, u = rr >> 2, g = rr & 3;
  int s = g * DD + u;
  o[n] = d ? (bib[s] + bhb[s]) : (bif[s] + bhf[s]);
}

// ---------------- GEMM: C[m,n] = sum_k A[m,k]*B[n,k] + bias[n], bf16 out ----------------
// XOR-swizzled LDS (pre-swizzled global source; per-thread-constant read slot qsw)
__global__ __launch_bounds__(256, 2)
void gemm_bt(const unsigned short* __restrict__ A, int lda,
             const unsigned short* __restrict__ B, int ldb,
             unsigned short* __restrict__ C, int ldc,
             const float* __restrict__ bias, int K)
{
  __shared__ unsigned short lA[128 * 32];
  __shared__ unsigned short lB[128 * 32];
  const int t = threadIdx.x;
  const int lane = t & 63;
  const int wv = t >> 6;
  const int wm = wv >> 1, wn = wv & 1;
  const int l15 = lane & 15, q = lane >> 4;
  const long m0 = (long)blockIdx.y * 128;
  const long n0 = (long)blockIdx.x * 128;
  const int rowS = t >> 2;
  const int kc = (((t & 3) ^ ((t >> 3) & 3))) * 8;         // swizzled source slot
  const int qsw = (q ^ ((l15 >> 1) & 3)) * 8;              // swizzled read slot
  const unsigned short* gA = A + (m0 + rowS) * lda + kc;
  const unsigned short* gB = B + (n0 + rowS) * ldb + kc;
  unsigned short* dA0 = lA + (wv << 9);
  unsigned short* dA1 = lA + 2048 + (wv << 9);
  unsigned short* dB0 = lB + (wv << 9);
  unsigned short* dB1 = lB + 2048 + (wv << 9);

  floatx4 acc[4][4];
  #pragma unroll
  for (int i = 0; i < 4; i++)
    #pragma unroll
    for (int j = 0; j < 4; j++)
      acc[i][j] = (floatx4){0.f, 0.f, 0.f, 0.f};

  const long a64 = (long)64 * lda;
  const long b64 = (long)64 * ldb;
  for (int kt = 0; kt < K; kt += 32) {
    gl_lds16(gA + kt,       dA0);
    gl_lds16(gA + a64 + kt, dA1);
    gl_lds16(gB + kt,       dB0);
    gl_lds16(gB + b64 + kt, dB1);
    __syncthreads();
    short8 af[4], bfr[4];
    #pragma unroll
    for (int i = 0; i < 4; i++)
      af[i] = *(const short8*)(lA + (wm * 64 + i * 16 + l15) * 32 + qsw);
    #pragma unroll
    for (int j = 0; j < 4; j++)
      bfr[j] = *(const short8*)(lB + (wn * 64 + j * 16 + l15) * 32 + qsw);
    #pragma unroll
    for (int i = 0; i < 4; i++)
      #pragma unroll
      for (int j = 0; j < 4; j++)
        acc[i][j] = __builtin_amdgcn_mfma_f32_16x16x32_bf16(af[i], bfr[j], acc[i][j], 0, 0, 0);
    __syncthreads();
  }

  #pragma unroll
  for (int i = 0; i < 4; i++) {
    #pragma unroll
    for (int j = 0; j < 4; j++) {
      const long mg = m0 + wm * 64 + i * 16 + q * 4;
      const long ng = n0 + wn * 64 + j * 16 + l15;
      const float bb = bias[ng];
      #pragma unroll
      for (int r = 0; r < 4; r++)
        C[(mg + r) * ldc + ng] = f2bf(acc[i][j][r] + bb);
    }
  }
}

// ---------------- persistent bidirectional LSTM recurrence ----------------
// Transposed MFMA (gates land in the 4 accumulator regs of each lane -> zero-shuffle
// epilogue, all 64 lanes active). h path fully coherent via sc1 loads/stores -> NO L2
// invalidation per step, so whh/xg stay L2-resident. Fragment LDS XOR-swizzled
// (pre-swizzled global_load_lds source; per-thread-constant read slot).
__global__ __launch_bounds__(256, 1)
void lstm_persist(const unsigned short* __restrict__ xg, int ldxg,
                  const unsigned short* __restrict__ whh,   // [2][3072][768] permuted
                  unsigned short* __restrict__ hbuf,        // [2][ndir][512][768]
                  unsigned short* __restrict__ outc,        // [16384][1536]
                  unsigned* bar,                            // 8 groups x 16 u32
                  int dir0, int ndir)
{
  __shared__ unsigned short bufA[16384];   // 4 panels [128][32], swizzled
  __shared__ unsigned short bufB[16384];   // 4 panels [128][32], swizzled
  __shared__ unsigned short xgs[16384];    // [128 rows][128 gate-cols], swizzled
  __shared__ unsigned short hout[128 * 40];// h staging, pad 40 (80B rows, 16B-aligned)

  const int bid = blockIdx.x;
  const int xcd = bid & 7;
  const int idx = bid >> 3;
  int dm, k3;
  if (ndir == 2) { dm = idx & 7; k3 = idx >> 3; }
  else           { dm = idx & 3; k3 = idx >> 2; }
  const int ld  = (ndir == 2) ? (dm & 1) : 0;
  const int dir = dir0 + ld;
  const int mt  = (ndir == 2) ? (dm >> 1) : dm;
  const int nt  = k3 * 8 + xcd;
  const int m0 = mt * 128, n0 = nt * 128;
  const int u0 = n0 >> 2;
  unsigned* gbar = bar + dm * 16;

  const int t0 = threadIdx.x;
  const int lane = t0 & 63;
  const int wv = t0 >> 6;
  const int wm = wv >> 1, wn = wv & 1;
  const int l15 = lane & 15, q = lane >> 4;
  const long ldoff = (ndir == 2 && ld == 1) ? (long)G4 : 0;

  const unsigned short* Bdir = whh + (long)dir * G4 * DD;
  // staging geometry: 16 rows x 64B per wave-instr; source slot pre-swizzled
  const int scolA = (((lane & 3) ^ ((lane >> 3) & 3))) * 8;  // shorts
  const int qsw   = (q ^ ((l15 >> 1) & 3)) * 8;              // fragment read slot (shorts)
  const int xsw   = l15 << 3;                                // xgs read swizzle (shorts)
  const int xsrc  = (((t0 & 15) ^ ((t0 >> 4) & 15))) * 8;    // xg staging source col (shorts)

  float c_reg[4][4];
  #pragma unroll
  for (int i = 0; i < 4; i++)
    #pragma unroll
    for (int j = 0; j < 4; j++)
      c_reg[i][j] = 0.f;

  for (int s = 0; s < BB; s++) {
    const int tt = dir ? (BB - 1 - s) : s;
    const unsigned short* hRead = hbuf + (((long)(s & 1)) * ndir + ld) * ((long)SS * DD);
    unsigned short* hw = hbuf + (((long)((s + 1) & 1)) * ndir + ld) * ((long)SS * DD);

    // stage xg tile [128 rows][128 cols] -> LDS (async, source pre-swizzled)
    {
      const unsigned short* xrow = xg + ((long)tt * SS + m0) * ldxg + ldoff + n0;
      #pragma unroll
      for (int c = 0; c < 8; c++) {
        int row = c * 16 + (t0 >> 4);
        gl_lds16(xrow + (long)row * ldxg + xsrc,
                 xgs + c * 2048 + wv * 512 + lane * 8);
      }
    }

    floatx4 acc[4][4];
    #pragma unroll
    for (int i = 0; i < 4; i++)
      #pragma unroll
      for (int j = 0; j < 4; j++)
        acc[i][j] = (floatx4){0.f, 0.f, 0.f, 0.f};

    for (int kt = 0; kt < 6; kt++) {
      const int kb = kt << 7;
      #pragma unroll
      for (int p = 0; p < 4; p++)
        #pragma unroll
        for (int rbh = 0; rbh < 2; rbh++) {
          int rb = (wv * 2 + rbh) * 16 + (lane >> 2);
          // A (h): coherent sc1 load -> fresh from L3, no L2 pollution/invalidation
          gl_lds16_c(hRead + (long)(m0 + rb) * DD + kb + p * 32 + scolA,
                     bufA + p * 4096 + (wv * 2 + rbh) * 512 + lane * 8);
          // B (whh): plain cached load -> stays L2-resident across all 32 steps
          gl_lds16(Bdir + (long)(n0 + rb) * DD + kb + p * 32 + scolA,
                   bufB + p * 4096 + (wv * 2 + rbh) * 512 + lane * 8);
        }
      __syncthreads();
      #pragma unroll
      for (int ks = 0; ks < 4; ks++) {
        short8 af[4], bfr[4];
        #pragma unroll
        for (int i = 0; i < 4; i++)
          af[i] = *(const short8*)(bufA + ks * 4096 + (wm * 64 + i * 16 + l15) * 32 + qsw);
        #pragma unroll
        for (int j = 0; j < 4; j++)
          bfr[j] = *(const short8*)(bufB + ks * 4096 + (wn * 64 + j * 16 + l15) * 32 + qsw);
        // TRANSPOSED: C[n][m]; each lane's 4 regs = gates i,f,g,o of one unit
        #pragma unroll
        for (int i = 0; i < 4; i++)
          #pragma unroll
          for (int j = 0; j < 4; j++)
            acc[i][j] = __builtin_amdgcn_mfma_f32_16x16x32_bf16(bfr[j], af[i], acc[i][j], 0, 0, 0);
      }
      __syncthreads();
    }

    // zero-shuffle gate epilogue: lane owns (m = ..+l15, unit u = (..+q*4)>>2)
    #pragma unroll
    for (int i = 0; i < 4; i++) {
      const int mrow = wm * 64 + i * 16 + l15;
      const int xbase = mrow * 128;
      #pragma unroll
      for (int j = 0; j < 4; j++) {
        const int nb = wn * 64 + j * 16 + q * 4;
        shortx4 xv = *(const shortx4*)(xgs + xbase + (nb ^ xsw));
        float gi = acc[i][j][0] + bf2f((unsigned short)xv[0]);
        float gf = acc[i][j][1] + bf2f((unsigned short)xv[1]);
        float gg = acc[i][j][2] + bf2f((unsigned short)xv[2]);
        float go = acc[i][j][3] + bf2f((unsigned short)xv[3]);
        float c = sigf(gf) * c_reg[i][j] + sigf(gi) * tanhfast(gg);
        float h = sigf(go) * tanhfast(c);
        c_reg[i][j] = c;
        hout[mrow * 40 + (nb >> 2)] = f2bf(h);
      }
    }
    __syncthreads();
    // coalesced output: 2 threads/row, 16 shorts each (2x16B)
    {
      const int row = t0 >> 1;
      const int half = t0 & 1;
      const unsigned short* src = hout + row * 40 + half * 16;
      short8 v0 = *(const short8*)(src);
      short8 v1 = *(const short8*)(src + 8);
      unsigned short* hwp = hw + (long)(m0 + row) * DD + u0 + half * 16;
      unsigned short* op  = outc + ((long)tt * SS + m0 + row) * IN2 + dir * DD + u0 + half * 16;
      store16_sc1(hwp, v0);
      store16_sc1(hwp + 8, v1);
      *(short8*)op = v0;
      *(short8*)(op + 8) = v1;
    }
    // drain the inline-asm sc1 stores (compiler doesn't track them) before arrival
    asm volatile("s_waitcnt vmcnt(0)" ::: "memory");
    if (s < BB - 1) grid_bar(gbar, 24);
  }
}

// ---------------- final linear [16384,1536](bf16) x [9,1536]^T ----------------
__global__ void final_linear(const unsigned short* __restrict__ xin, const float* __restrict__ w,
                             const float* __restrict__ b, float* __restrict__ out)
{
  __shared__ float red[NCLS * 256];
  int row = blockIdx.x;
  const unsigned short* x = xin + (long)row * IN2;
  float p[NCLS];
  #pragma unroll
  for (int c = 0; c < NCLS; c++) p[c] = 0.f;
  for (int k = threadIdx.x; k < IN2; k += 256) {
    float xv = bf2f(x[k]);
    #pragma unroll
    for (int c = 0; c < NCLS; c++) p[c] += xv * w[c * IN2 + k];
  }
  #pragma unroll
  for (int c = 0; c < NCLS; c++) red[c * 256 + threadIdx.x] = p[c];
  __syncthreads();
  for (int s = 128; s > 0; s >>= 1) {
    if (threadIdx.x < s) {
      #pragma unroll
      for (int c = 0; c < NCLS; c++)
        red[c * 256 + threadIdx.x] += red[c * 256 + threadIdx.x + s];
    }
    __syncthreads();
  }
  if (threadIdx.x < NCLS)
    out[(long)row * NCLS + threadIdx.x] = red[threadIdx.x * 256] + b[threadIdx.x];
}

extern "C" void kernel_launch(void* const* d_in, const int* in_sizes, int n_in,
                              void* d_out, int out_size, void* d_ws, size_t ws_size,
                              hipStream_t stream)
{
  const int*   batch  = (const int*)d_in[0];
  const float* hidden = (const float*)d_in[1];
  const float* w_ih_f = (const float*)d_in[2];
  const float* w_hh_f = (const float*)d_in[3];
  const float* b_ih_f = (const float*)d_in[4];
  const float* b_hh_f = (const float*)d_in[5];
  const float* w_ih_b = (const float*)d_in[6];
  const float* w_hh_b = (const float*)d_in[7];
  const float* b_ih_b = (const float*)d_in[8];
  const float* b_hh_b = (const float*)d_in[9];
  const float* lin_w  = (const float*)d_in[10];
  const float* lin_b  = (const float*)d_in[11];
  float* out = (float*)d_out;

  char* ws = (char*)d_ws;
  size_t off = 0;
  auto alloc = [&](size_t bytes) -> char* {
    char* p = ws + off;
    off += (bytes + 255) & ~(size_t)255;
    return p;
  };

  const size_t SZ_XG_A = (size_t)ROWS * NB2 * 2;      // 201.3 MB
  const size_t SZ_XG_B = (size_t)ROWS * G4  * 2;      // 100.7 MB
  const size_t SZ_XBF  = (size_t)ROWS * IN2 * 2;      //  50.3 MB
  const size_t SZ_W    = (size_t)G4 * IN2 * 2;        //   9.4 MB
  const size_t SZ_BIAS = (size_t)NB2 * 4;
  const size_t SZ_HBUF = (size_t)2 * 2 * SS * DD * 2; //   3.1 MB
  const size_t SZ_BAR  = 512;
  const size_t SZ_SUMS = (size_t)VOCAB * DD * 4 + (size_t)VOCAB * 4;

  const size_t NEED_C = SZ_XG_A + SZ_XBF + SZ_W + SZ_BIAS + SZ_HBUF + SZ_BAR + 8 * 256;
  const bool combined = ws_size >= NEED_C;

  const long nWIH = (long)G4 * IN2;
  const long nWHH = (long)G4 * DD;

  if (combined) {
    unsigned short* xg   = (unsigned short*)alloc(SZ_XG_A);
    unsigned short* xbf  = (unsigned short*)alloc(SZ_XBF);   // x input, later reused as outc
    unsigned short* wbuf = (unsigned short*)alloc(SZ_W);     // wih_f -> wih_b -> whh(both)
    float*          bias = (float*)alloc(SZ_BIAS);
    unsigned short* hbuf = (unsigned short*)alloc(SZ_HBUF);
    unsigned*       bar  = (unsigned*)alloc(SZ_BAR);
    float* sums   = (float*)xg;                              // overlay, consumed pre-xg-GEMM
    float* counts = sums + (size_t)VOCAB * DD;

    hipMemsetAsync(sums, 0, SZ_SUMS, stream);
    hipMemsetAsync(bar, 0, SZ_BAR, stream);
    seg_scatter<<<ROWS, 256, 0, stream>>>(batch, hidden, sums, counts);
    build_x<<<ROWS, 256, 0, stream>>>(batch, hidden, sums, counts, xbf);
    conv_bias_perm<<<(NB2 + 255) / 256, 256, 0, stream>>>(b_ih_f, b_hh_f, b_ih_b, b_hh_b, bias);

    for (int dir = 0; dir < 2; dir++) {
      conv_w_perm<<<(unsigned)((nWIH + 255) / 256), 256, 0, stream>>>(dir ? w_ih_b : w_ih_f, wbuf, IN2);
      dim3 grid(G4 / 128, ROWS / 128, 1);
      gemm_bt<<<grid, 256, 0, stream>>>(xbf, IN2, wbuf, IN2,
                                        xg + (size_t)dir * G4, NB2,
                                        bias + (size_t)dir * G4, IN2);
    }
    conv_w_perm<<<(unsigned)((nWHH + 255) / 256), 256, 0, stream>>>(w_hh_f, wbuf, DD);
    conv_w_perm<<<(unsigned)((nWHH + 255) / 256), 256, 0, stream>>>(w_hh_b, wbuf + (size_t)G4 * DD, DD);

    hipMemsetAsync(hbuf, 0, SZ_HBUF, stream);
    lstm_persist<<<192, 256, 0, stream>>>(xg, NB2, wbuf, hbuf, xbf, bar, 0, 2);
    final_linear<<<ROWS, 256, 0, stream>>>(xbf, lin_w, lin_b, out);
  } else {
    // direction-sequential (~223 MB, proven to fit)
    unsigned short* xg   = (unsigned short*)alloc(SZ_XG_B);
    unsigned short* xbf  = (unsigned short*)alloc(SZ_XBF);
    unsigned short* outc = (unsigned short*)alloc(SZ_XBF);
    unsigned short* wih  = (unsigned short*)alloc(SZ_W);
    unsigned short* whh  = (unsigned short*)alloc(SZ_W);
    float*          bias = (float*)alloc(SZ_BIAS);
    unsigned short* hbuf = (unsigned short*)alloc(SZ_HBUF);
    unsigned*       bar  = (unsigned*)alloc(SZ_BAR);
    float* sums   = (float*)xg;
    float* counts = sums + (size_t)VOCAB * DD;

    hipMemsetAsync(sums, 0, SZ_SUMS, stream);
    hipMemsetAsync(bar, 0, SZ_BAR, stream);
    seg_scatter<<<ROWS, 256, 0, stream>>>(batch, hidden, sums, counts);
    build_x<<<ROWS, 256, 0, stream>>>(batch, hidden, sums, counts, xbf);
    conv_bias_perm<<<(NB2 + 255) / 256, 256, 0, stream>>>(b_ih_f, b_hh_f, b_ih_b, b_hh_b, bias);
    conv_w_perm<<<(unsigned)((nWHH + 255) / 256), 256, 0, stream>>>(w_hh_f, whh, DD);
    conv_w_perm<<<(unsigned)((nWHH + 255) / 256), 256, 0, stream>>>(w_hh_b, whh + (size_t)G4 * DD, DD);

    for (int dir = 0; dir < 2; dir++) {
      conv_w_perm<<<(unsigned)((nWIH + 255) / 256), 256, 0, stream>>>(dir ? w_ih_b : w_ih_f, wih, IN2);
      {
        dim3 grid(G4 / 128, ROWS / 128, 1);
        gemm_bt<<<grid, 256, 0, stream>>>(xbf, IN2, wih, IN2, xg, G4,
                                          bias + (size_t)dir * G4, IN2);
      }
      hipMemsetAsync(hbuf, 0, SZ_HBUF, stream);
      lstm_persist<<<96, 256, 0, stream>>>(xg, G4, whh, hbuf, outc, bar, dir, 1);
    }
    final_linear<<<ROWS, 256, 0, stream>>>(outc, lin_w, lin_b, out);
  }
}

// Round 2
// 1250.979 us; speedup vs baseline: 1.4944x; 1.0469x over previous
//
#include <hip/hip_runtime.h>

#define VOCAB 28996
#define BB 32
#define SS 512
#define DD 768
#define NCLS 9
#define ROWS (BB*SS)     // 16384
#define IN2 (2*DD)       // 1536
#define G4 (4*DD)        // 3072
#define NB2 (2*G4)       // 6144

typedef __attribute__((ext_vector_type(8))) short short8;
typedef __attribute__((ext_vector_type(4))) short shortx4;
typedef __attribute__((ext_vector_type(4))) float floatx4;
typedef unsigned long long ull;

__device__ __forceinline__ float bf2f(unsigned short u){
  union { unsigned int i; float f; } v; v.i = ((unsigned int)u) << 16; return v.f;
}
__device__ __forceinline__ unsigned short f2bf(float f){
  union { float f; unsigned int i; } v; v.f = f;
  unsigned int r = v.i + 0x7FFFu + ((v.i >> 16) & 1u);
  return (unsigned short)(r >> 16);
}
__device__ __forceinline__ float sigf(float x){ return 1.0f / (1.0f + __expf(-x)); }
__device__ __forceinline__ float tanhfast(float x){
  float y = fminf(fmaxf(x, -15.f), 15.f);
  float e = __expf(2.f * y);
  return 1.f - 2.f / (e + 1.f);
}

__device__ __forceinline__ void gl_lds16(const unsigned short* g, unsigned short* l){
  __builtin_amdgcn_global_load_lds((__attribute__((address_space(1))) void*)(g),
                                   (__attribute__((address_space(3))) void*)(l), 16, 0, 0);
}
// coherent variant: sc0|sc1 -> bypass L1+L2, read memory-side L3 (h path only)
__device__ __forceinline__ void gl_lds16_c(const unsigned short* g, unsigned short* l){
  __builtin_amdgcn_global_load_lds((__attribute__((address_space(1))) void*)(g),
                                   (__attribute__((address_space(3))) void*)(l), 16, 0, 17);
}
// write-through store to the coherence point (L3) so sc1 readers on other XCDs see it
__device__ __forceinline__ void store16_sc1(unsigned short* p, short8 v){
  asm volatile("global_store_dwordx4 %0, %1, off sc0 sc1" :: "v"(p), "v"(v) : "memory");
}

// ---- group barrier: relaxed sc1 atomics for arrival/spin. NO acquire fence --
// h freshness comes from sc1 loads (bypass L2), so whh/xg stay L2-resident. ----
__device__ __forceinline__ void grid_bar(unsigned* bar, int nb)
{
  __syncthreads();
  if (threadIdx.x == 0) {
    unsigned g = __hip_atomic_load(bar + 1, __ATOMIC_RELAXED, __HIP_MEMORY_SCOPE_AGENT);
    unsigned a = __hip_atomic_fetch_add(bar, 1u, __ATOMIC_RELAXED, __HIP_MEMORY_SCOPE_AGENT);
    if (a == (unsigned)(nb - 1)) {
      __hip_atomic_store(bar, 0u, __ATOMIC_RELAXED, __HIP_MEMORY_SCOPE_AGENT);
      __hip_atomic_store(bar + 1, g + 1u, __ATOMIC_RELEASE, __HIP_MEMORY_SCOPE_AGENT);
    } else {
      unsigned cur;
      do {
        __builtin_amdgcn_s_sleep(2);
        cur = __hip_atomic_load(bar + 1, __ATOMIC_RELAXED, __HIP_MEMORY_SCOPE_AGENT);
      } while (cur == g);
    }
  }
  __syncthreads();
}

// ---------------- segment mean ----------------
__global__ void seg_scatter(const int* __restrict__ ids, const float* __restrict__ hidden,
                            float* __restrict__ sums, float* __restrict__ counts)
{
  int r = blockIdx.x;
  int id = ids[r];
  const float* h = hidden + (long)r * DD;
  float* s = sums + (long)id * DD;
  for (int d = threadIdx.x; d < DD; d += 256)
    atomicAdd(&s[d], h[d]);
  if (threadIdx.x == 0) atomicAdd(&counts[id], 1.0f);
}

__global__ void build_x(const int* __restrict__ ids, const float* __restrict__ hidden,
                        const float* __restrict__ sums, const float* __restrict__ counts,
                        unsigned short* __restrict__ x)
{
  int r = blockIdx.x;
  int id = ids[r];
  float inv = 1.0f / fmaxf(counts[id], 1.0f);
  const float* h = hidden + (long)r * DD;
  const float* s = sums + (long)id * DD;
  unsigned short* xr = x + (long)r * IN2;
  for (int d = threadIdx.x; d < DD; d += 256) {
    xr[d]      = f2bf(h[d]);
    xr[DD + d] = f2bf(s[d] * inv);
  }
}

// -------- weight conversion with gate-interleave permutation: row' = u*4+g <- row g*768+u --------
__global__ void conv_w_perm(const float* __restrict__ w, unsigned short* __restrict__ o, int K)
{
  long i = (long)blockIdx.x * 256 + threadIdx.x;
  if (i >= (long)G4 * K) return;
  int row = (int)(i / K); int k = (int)(i - (long)row * K);
  int u = row >> 2, g = row & 3;
  o[i] = f2bf(w[((long)(g * DD + u)) * K + k]);
}

__global__ void conv_bias_perm(const float* __restrict__ bif, const float* __restrict__ bhf,
                               const float* __restrict__ bib, const float* __restrict__ bhb,
                               float* __restrict__ o)
{
  int n = blockIdx.x * 256 + threadIdx.x;
  if (n >= NB2) return;
  int d = n / G4, rr = n - d * G4, u = rr >> 2, g = rr & 3;
  int s = g * DD + u;
  o[n] = d ? (bib[s] + bhb[s]) : (bif[s] + bhf[s]);
}

// ---------------- GEMM: C[m,n] = sum_k A[m,k]*B[n,k] + bias[n], bf16 out ----------------
__global__ __launch_bounds__(256, 2)
void gemm_bt(const unsigned short* __restrict__ A, int lda,
             const unsigned short* __restrict__ B, int ldb,
             unsigned short* __restrict__ C, int ldc,
             const float* __restrict__ bias, int K)
{
  __shared__ unsigned short lA[128 * 32];
  __shared__ unsigned short lB[128 * 32];
  const int t = threadIdx.x;
  const int lane = t & 63;
  const int wv = t >> 6;
  const int wm = wv >> 1, wn = wv & 1;
  const int l15 = lane & 15, q = lane >> 4;
  const long m0 = (long)blockIdx.y * 128;
  const long n0 = (long)blockIdx.x * 128;
  const int rowS = t >> 2;
  const int kc = (((t & 3) ^ ((t >> 3) & 3))) * 8;         // swizzled source slot
  const int qsw = (q ^ ((l15 >> 1) & 3)) * 8;              // swizzled read slot
  const unsigned short* gA = A + (m0 + rowS) * lda + kc;
  const unsigned short* gB = B + (n0 + rowS) * ldb + kc;
  unsigned short* dA0 = lA + (wv << 9);
  unsigned short* dA1 = lA + 2048 + (wv << 9);
  unsigned short* dB0 = lB + (wv << 9);
  unsigned short* dB1 = lB + 2048 + (wv << 9);

  floatx4 acc[4][4];
  #pragma unroll
  for (int i = 0; i < 4; i++)
    #pragma unroll
    for (int j = 0; j < 4; j++)
      acc[i][j] = (floatx4){0.f, 0.f, 0.f, 0.f};

  const long a64 = (long)64 * lda;
  const long b64 = (long)64 * ldb;
  for (int kt = 0; kt < K; kt += 32) {
    gl_lds16(gA + kt,       dA0);
    gl_lds16(gA + a64 + kt, dA1);
    gl_lds16(gB + kt,       dB0);
    gl_lds16(gB + b64 + kt, dB1);
    __syncthreads();
    short8 af[4], bfr[4];
    #pragma unroll
    for (int i = 0; i < 4; i++)
      af[i] = *(const short8*)(lA + (wm * 64 + i * 16 + l15) * 32 + qsw);
    #pragma unroll
    for (int j = 0; j < 4; j++)
      bfr[j] = *(const short8*)(lB + (wn * 64 + j * 16 + l15) * 32 + qsw);
    #pragma unroll
    for (int i = 0; i < 4; i++)
      #pragma unroll
      for (int j = 0; j < 4; j++)
        acc[i][j] = __builtin_amdgcn_mfma_f32_16x16x32_bf16(af[i], bfr[j], acc[i][j], 0, 0, 0);
    __syncthreads();
  }

  #pragma unroll
  for (int i = 0; i < 4; i++) {
    #pragma unroll
    for (int j = 0; j < 4; j++) {
      const long mg = m0 + wm * 64 + i * 16 + q * 4;
      const long ng = n0 + wn * 64 + j * 16 + l15;
      const float bb = bias[ng];
      #pragma unroll
      for (int r = 0; r < 4; r++)
        C[(mg + r) * ldc + ng] = f2bf(acc[i][j][r] + bb);
    }
  }
}

// ---------------- persistent bidirectional LSTM recurrence ----------------
// 512 threads = 8 waves = 2 waves/SIMD (was 1/SIMD): overlaps ds_read->MFMA chains,
// staging drains, and epilogue VALU between co-resident waves. Transposed MFMA
// zero-shuffle epilogue; sc1-coherent h path; XOR-swizzled LDS; xgs double-buffered
// with next-step prefetch issued before the grid barrier (HBM latency hides under
// barrier arrival skew).
__global__ __launch_bounds__(512, 1)
void lstm_persist(const unsigned short* __restrict__ xg, int ldxg,
                  const unsigned short* __restrict__ whh,   // [2][3072][768] permuted
                  unsigned short* __restrict__ hbuf,        // [2][ndir][512][768]
                  unsigned short* __restrict__ outc,        // [16384][1536]
                  unsigned* bar,                            // 8 groups x 16 u32
                  int dir0, int ndir)
{
  __shared__ unsigned short bufA[16384];      // 4 panels [128][32], swizzled
  __shared__ unsigned short bufB[16384];      // 4 panels [128][32], swizzled
  __shared__ unsigned short xgs[2][16384];    // double-buffered [128][128], swizzled
  __shared__ unsigned short hout[128 * 40];   // h staging, pad 40

  const int bid = blockIdx.x;
  const int xcd = bid & 7;
  const int idx = bid >> 3;
  int dm, k3;
  if (ndir == 2) { dm = idx & 7; k3 = idx >> 3; }
  else           { dm = idx & 3; k3 = idx >> 2; }
  const int ld  = (ndir == 2) ? (dm & 1) : 0;
  const int dir = dir0 + ld;
  const int mt  = (ndir == 2) ? (dm >> 1) : dm;
  const int nt  = k3 * 8 + xcd;
  const int m0 = mt * 128, n0 = nt * 128;
  const int u0 = n0 >> 2;
  unsigned* gbar = bar + dm * 16;

  const int t0 = threadIdx.x;
  const int lane = t0 & 63;
  const int wv = t0 >> 6;            // 0..7
  const int wm = wv >> 1;            // 0..3 : 32-row band
  const int wn = wv & 1;             // 0..1 : 64-col half
  const int l15 = lane & 15, q = lane >> 4;
  const long ldoff = (ndir == 2 && ld == 1) ? (long)G4 : 0;

  const unsigned short* Bdir = whh + (long)dir * G4 * DD;
  const int srow  = lane >> 2;                               // 0..15
  const int scolA = (((lane & 3) ^ ((lane >> 3) & 3))) * 8;  // staging source slot
  const int qsw   = (q ^ ((l15 >> 1) & 3)) * 8;              // fragment read slot
  const int xsw   = l15 << 3;                                // xgs read swizzle
  const int xsrc  = (((t0 & 15) ^ ((t0 >> 4) & 15))) * 8;    // xg staging source col

  float c_reg[2][4];
  #pragma unroll
  for (int i = 0; i < 2; i++)
    #pragma unroll
    for (int j = 0; j < 4; j++)
      c_reg[i][j] = 0.f;

  // prefetch step 0's xg tile into xgs[0]
  {
    const int tt0 = dir ? (BB - 1) : 0;
    const unsigned short* xrow = xg + ((long)tt0 * SS + m0) * ldxg + ldoff + n0;
    #pragma unroll
    for (int c = 0; c < 4; c++) {
      int row = c * 32 + (t0 >> 4);
      gl_lds16(xrow + (long)row * ldxg + xsrc,
               xgs[0] + c * 4096 + (t0 >> 4) * 128 + (t0 & 15) * 8);
    }
  }

  for (int s = 0; s < BB; s++) {
    const int tt = dir ? (BB - 1 - s) : s;
    const unsigned short* hRead = hbuf + (((long)(s & 1)) * ndir + ld) * ((long)SS * DD);
    unsigned short* hw = hbuf + (((long)((s + 1) & 1)) * ndir + ld) * ((long)SS * DD);
    const unsigned short* xcur = xgs[s & 1];

    floatx4 acc[2][4];
    #pragma unroll
    for (int i = 0; i < 2; i++)
      #pragma unroll
      for (int j = 0; j < 4; j++)
        acc[i][j] = (floatx4){0.f, 0.f, 0.f, 0.f};

    for (int kt = 0; kt < 6; kt++) {
      const int kb = kt << 7;
      const int rb = wv * 16 + srow;   // 0..127 across 8 waves
      #pragma unroll
      for (int p = 0; p < 4; p++) {
        // A (h): coherent sc1 load -> fresh from L3, no L2 pollution (issued first: longest latency)
        gl_lds16_c(hRead + (long)(m0 + rb) * DD + kb + p * 32 + scolA,
                   bufA + p * 4096 + wv * 512 + lane * 8);
        // B (whh): plain cached load -> L2-resident across all 32 steps
        gl_lds16(Bdir + (long)(n0 + rb) * DD + kb + p * 32 + scolA,
                 bufB + p * 4096 + wv * 512 + lane * 8);
      }
      __syncthreads();
      #pragma unroll
      for (int ks = 0; ks < 4; ks++) {
        short8 af[2], bfr[4];
        #pragma unroll
        for (int i = 0; i < 2; i++)
          af[i] = *(const short8*)(bufA + ks * 4096 + (wm * 32 + i * 16 + l15) * 32 + qsw);
        #pragma unroll
        for (int j = 0; j < 4; j++)
          bfr[j] = *(const short8*)(bufB + ks * 4096 + (wn * 64 + j * 16 + l15) * 32 + qsw);
        // TRANSPOSED: each lane's 4 acc regs = gates i,f,g,o of one unit
        #pragma unroll
        for (int i = 0; i < 2; i++)
          #pragma unroll
          for (int j = 0; j < 4; j++)
            acc[i][j] = __builtin_amdgcn_mfma_f32_16x16x32_bf16(bfr[j], af[i], acc[i][j], 0, 0, 0);
      }
      __syncthreads();
    }

    // zero-shuffle gate epilogue
    #pragma unroll
    for (int i = 0; i < 2; i++) {
      const int mrow = wm * 32 + i * 16 + l15;
      const int xbase = mrow * 128;
      #pragma unroll
      for (int j = 0; j < 4; j++) {
        const int nb = wn * 64 + j * 16 + q * 4;
        shortx4 xv = *(const shortx4*)(xcur + xbase + (nb ^ xsw));
        float gi = acc[i][j][0] + bf2f((unsigned short)xv[0]);
        float gf = acc[i][j][1] + bf2f((unsigned short)xv[1]);
        float gg = acc[i][j][2] + bf2f((unsigned short)xv[2]);
        float go = acc[i][j][3] + bf2f((unsigned short)xv[3]);
        float c = sigf(gf) * c_reg[i][j] + sigf(gi) * tanhfast(gg);
        float h = sigf(go) * tanhfast(c);
        c_reg[i][j] = c;
        hout[mrow * 40 + (nb >> 2)] = f2bf(h);
      }
    }
    __syncthreads();
    // coalesced output: 4 threads/row, 8 shorts (16B) each
    {
      const int row = t0 >> 2;
      const int qq = t0 & 3;
      short8 v0 = *(const short8*)(hout + row * 40 + qq * 8);
      unsigned short* hwp = hw + (long)(m0 + row) * DD + u0 + qq * 8;
      unsigned short* op  = outc + ((long)tt * SS + m0 + row) * IN2 + dir * DD + u0 + qq * 8;
      store16_sc1(hwp, v0);
      *(short8*)op = v0;
    }
    // drain the inline-asm sc1 stores before arrival
    asm volatile("s_waitcnt vmcnt(0)" ::: "memory");
    if (s < BB - 1) {
      // prefetch next step's xg tile into the other buffer; its latency hides
      // under barrier arrival skew (drained at grid_bar's entry syncthreads)
      const int tn = dir ? (BB - 2 - s) : (s + 1);
      const unsigned short* xrow = xg + ((long)tn * SS + m0) * ldxg + ldoff + n0;
      unsigned short* xnxt = xgs[(s + 1) & 1];
      #pragma unroll
      for (int c = 0; c < 4; c++) {
        int row = c * 32 + (t0 >> 4);
        gl_lds16(xrow + (long)row * ldxg + xsrc,
                 xnxt + c * 4096 + (t0 >> 4) * 128 + (t0 & 15) * 8);
      }
      grid_bar(gbar, 24);
    }
  }
}

// ---------------- final linear [16384,1536](bf16) x [9,1536]^T ----------------
__global__ void final_linear(const unsigned short* __restrict__ xin, const float* __restrict__ w,
                             const float* __restrict__ b, float* __restrict__ out)
{
  __shared__ float red[NCLS * 256];
  int row = blockIdx.x;
  const unsigned short* x = xin + (long)row * IN2;
  float p[NCLS];
  #pragma unroll
  for (int c = 0; c < NCLS; c++) p[c] = 0.f;
  for (int k = threadIdx.x; k < IN2; k += 256) {
    float xv = bf2f(x[k]);
    #pragma unroll
    for (int c = 0; c < NCLS; c++) p[c] += xv * w[c * IN2 + k];
  }
  #pragma unroll
  for (int c = 0; c < NCLS; c++) red[c * 256 + threadIdx.x] = p[c];
  __syncthreads();
  for (int s = 128; s > 0; s >>= 1) {
    if (threadIdx.x < s) {
      #pragma unroll
      for (int c = 0; c < NCLS; c++)
        red[c * 256 + threadIdx.x] += red[c * 256 + threadIdx.x + s];
    }
    __syncthreads();
  }
  if (threadIdx.x < NCLS)
    out[(long)row * NCLS + threadIdx.x] = red[threadIdx.x * 256] + b[threadIdx.x];
}

extern "C" void kernel_launch(void* const* d_in, const int* in_sizes, int n_in,
                              void* d_out, int out_size, void* d_ws, size_t ws_size,
                              hipStream_t stream)
{
  const int*   batch  = (const int*)d_in[0];
  const float* hidden = (const float*)d_in[1];
  const float* w_ih_f = (const float*)d_in[2];
  const float* w_hh_f = (const float*)d_in[3];
  const float* b_ih_f = (const float*)d_in[4];
  const float* b_hh_f = (const float*)d_in[5];
  const float* w_ih_b = (const float*)d_in[6];
  const float* w_hh_b = (const float*)d_in[7];
  const float* b_ih_b = (const float*)d_in[8];
  const float* b_hh_b = (const float*)d_in[9];
  const float* lin_w  = (const float*)d_in[10];
  const float* lin_b  = (const float*)d_in[11];
  float* out = (float*)d_out;

  char* ws = (char*)d_ws;
  size_t off = 0;
  auto alloc = [&](size_t bytes) -> char* {
    char* p = ws + off;
    off += (bytes + 255) & ~(size_t)255;
    return p;
  };

  const size_t SZ_XG_A = (size_t)ROWS * NB2 * 2;      // 201.3 MB
  const size_t SZ_XG_B = (size_t)ROWS * G4  * 2;      // 100.7 MB
  const size_t SZ_XBF  = (size_t)ROWS * IN2 * 2;      //  50.3 MB
  const size_t SZ_W    = (size_t)G4 * IN2 * 2;        //   9.4 MB
  const size_t SZ_BIAS = (size_t)NB2 * 4;
  const size_t SZ_HBUF = (size_t)2 * 2 * SS * DD * 2; //   3.1 MB
  const size_t SZ_BAR  = 512;
  const size_t SZ_SUMS = (size_t)VOCAB * DD * 4 + (size_t)VOCAB * 4;

  const size_t NEED_C = SZ_XG_A + SZ_XBF + SZ_W + SZ_BIAS + SZ_HBUF + SZ_BAR + 8 * 256;
  const bool combined = ws_size >= NEED_C;

  const long nWIH = (long)G4 * IN2;
  const long nWHH = (long)G4 * DD;

  if (combined) {
    unsigned short* xg   = (unsigned short*)alloc(SZ_XG_A);
    unsigned short* xbf  = (unsigned short*)alloc(SZ_XBF);   // x input, later reused as outc
    unsigned short* wbuf = (unsigned short*)alloc(SZ_W);     // wih_f -> wih_b -> whh(both)
    float*          bias = (float*)alloc(SZ_BIAS);
    unsigned short* hbuf = (unsigned short*)alloc(SZ_HBUF);
    unsigned*       bar  = (unsigned*)alloc(SZ_BAR);
    float* sums   = (float*)xg;                              // overlay, consumed pre-xg-GEMM
    float* counts = sums + (size_t)VOCAB * DD;

    hipMemsetAsync(sums, 0, SZ_SUMS, stream);
    hipMemsetAsync(bar, 0, SZ_BAR, stream);
    seg_scatter<<<ROWS, 256, 0, stream>>>(batch, hidden, sums, counts);
    build_x<<<ROWS, 256, 0, stream>>>(batch, hidden, sums, counts, xbf);
    conv_bias_perm<<<(NB2 + 255) / 256, 256, 0, stream>>>(b_ih_f, b_hh_f, b_ih_b, b_hh_b, bias);

    for (int dir = 0; dir < 2; dir++) {
      conv_w_perm<<<(unsigned)((nWIH + 255) / 256), 256, 0, stream>>>(dir ? w_ih_b : w_ih_f, wbuf, IN2);
      dim3 grid(G4 / 128, ROWS / 128, 1);
      gemm_bt<<<grid, 256, 0, stream>>>(xbf, IN2, wbuf, IN2,
                                        xg + (size_t)dir * G4, NB2,
                                        bias + (size_t)dir * G4, IN2);
    }
    conv_w_perm<<<(unsigned)((nWHH + 255) / 256), 256, 0, stream>>>(w_hh_f, wbuf, DD);
    conv_w_perm<<<(unsigned)((nWHH + 255) / 256), 256, 0, stream>>>(w_hh_b, wbuf + (size_t)G4 * DD, DD);

    hipMemsetAsync(hbuf, 0, SZ_HBUF, stream);
    lstm_persist<<<192, 512, 0, stream>>>(xg, NB2, wbuf, hbuf, xbf, bar, 0, 2);
    final_linear<<<ROWS, 256, 0, stream>>>(xbf, lin_w, lin_b, out);
  } else {
    // direction-sequential (~223 MB, proven to fit)
    unsigned short* xg   = (unsigned short*)alloc(SZ_XG_B);
    unsigned short* xbf  = (unsigned short*)alloc(SZ_XBF);
    unsigned short* outc = (unsigned short*)alloc(SZ_XBF);
    unsigned short* wih  = (unsigned short*)alloc(SZ_W);
    unsigned short* whh  = (unsigned short*)alloc(SZ_W);
    float*          bias = (float*)alloc(SZ_BIAS);
    unsigned short* hbuf = (unsigned short*)alloc(SZ_HBUF);
    unsigned*       bar  = (unsigned*)alloc(SZ_BAR);
    float* sums   = (float*)xg;
    float* counts = sums + (size_t)VOCAB * DD;

    hipMemsetAsync(sums, 0, SZ_SUMS, stream);
    hipMemsetAsync(bar, 0, SZ_BAR, stream);
    seg_scatter<<<ROWS, 256, 0, stream>>>(batch, hidden, sums, counts);
    build_x<<<ROWS, 256, 0, stream>>>(batch, hidden, sums, counts, xbf);
    conv_bias_perm<<<(NB2 + 255) / 256, 256, 0, stream>>>(b_ih_f, b_hh_f, b_ih_b, b_hh_b, bias);
    conv_w_perm<<<(unsigned)((nWHH + 255) / 256), 256, 0, stream>>>(w_hh_f, whh, DD);
    conv_w_perm<<<(unsigned)((nWHH + 255) / 256), 256, 0, stream>>>(w_hh_b, whh + (size_t)G4 * DD, DD);

    for (int dir = 0; dir < 2; dir++) {
      conv_w_perm<<<(unsigned)((nWIH + 255) / 256), 256, 0, stream>>>(dir ? w_ih_b : w_ih_f, wih, IN2);
      {
        dim3 grid(G4 / 128, ROWS / 128, 1);
        gemm_bt<<<grid, 256, 0, stream>>>(xbf, IN2, wih, IN2, xg, G4,
                                          bias + (size_t)dir * G4, IN2);
      }
      hipMemsetAsync(hbuf, 0, SZ_HBUF, stream);
      lstm_persist<<<96, 512, 0, stream>>>(xg, G4, whh, hbuf, outc, bar, dir, 1);
    }
    final_linear<<<ROWS, 256, 0, stream>>>(outc, lin_w, lin_b, out);
  }
}

// Round 3
// 1225.478 us; speedup vs baseline: 1.5255x; 1.0208x over previous
//
#include <hip/hip_runtime.h>

#define VOCAB 28996
#define BB 32
#define SS 512
#define DD 768
#define NCLS 9
#define ROWS (BB*SS)     // 16384
#define IN2 (2*DD)       // 1536
#define G4 (4*DD)        // 3072
#define NB2 (2*G4)       // 6144

typedef __attribute__((ext_vector_type(8))) short short8;
typedef __attribute__((ext_vector_type(4))) short shortx4;
typedef __attribute__((ext_vector_type(4))) float floatx4;
typedef unsigned long long ull;

__device__ __forceinline__ float bf2f(unsigned short u){
  union { unsigned int i; float f; } v; v.i = ((unsigned int)u) << 16; return v.f;
}
__device__ __forceinline__ unsigned short f2bf(float f){
  union { float f; unsigned int i; } v; v.f = f;
  unsigned int r = v.i + 0x7FFFu + ((v.i >> 16) & 1u);
  return (unsigned short)(r >> 16);
}
__device__ __forceinline__ float sigf(float x){ return 1.0f / (1.0f + __expf(-x)); }
__device__ __forceinline__ float tanhfast(float x){
  float y = fminf(fmaxf(x, -15.f), 15.f);
  float e = __expf(2.f * y);
  return 1.f - 2.f / (e + 1.f);
}

__device__ __forceinline__ void gl_lds16(const unsigned short* g, unsigned short* l){
  __builtin_amdgcn_global_load_lds((__attribute__((address_space(1))) void*)(g),
                                   (__attribute__((address_space(3))) void*)(l), 16, 0, 0);
}
// coherent variant: sc0|sc1 -> bypass L1+L2, read memory-side L3 (h path only)
__device__ __forceinline__ void gl_lds16_c(const unsigned short* g, unsigned short* l){
  __builtin_amdgcn_global_load_lds((__attribute__((address_space(1))) void*)(g),
                                   (__attribute__((address_space(3))) void*)(l), 16, 0, 17);
}
// write-through store to the coherence point (L3) so sc1 readers on other XCDs see it
__device__ __forceinline__ void store16_sc1(unsigned short* p, short8 v){
  asm volatile("global_store_dwordx4 %0, %1, off sc0 sc1" :: "v"(p), "v"(v) : "memory");
}

#define VMCNT(n) do { asm volatile("s_waitcnt vmcnt(" #n ")" ::: "memory"); \
                      __builtin_amdgcn_sched_barrier(0); } while (0)

// ---------------- segment mean ----------------
__global__ void seg_scatter(const int* __restrict__ ids, const float* __restrict__ hidden,
                            float* __restrict__ sums, float* __restrict__ counts)
{
  int r = blockIdx.x;
  int id = ids[r];
  const float* h = hidden + (long)r * DD;
  float* s = sums + (long)id * DD;
  for (int d = threadIdx.x; d < DD; d += 256)
    atomicAdd(&s[d], h[d]);
  if (threadIdx.x == 0) atomicAdd(&counts[id], 1.0f);
}

__global__ void build_x(const int* __restrict__ ids, const float* __restrict__ hidden,
                        const float* __restrict__ sums, const float* __restrict__ counts,
                        unsigned short* __restrict__ x)
{
  int r = blockIdx.x;
  int id = ids[r];
  float inv = 1.0f / fmaxf(counts[id], 1.0f);
  const float* h = hidden + (long)r * DD;
  const float* s = sums + (long)id * DD;
  unsigned short* xr = x + (long)r * IN2;
  for (int d = threadIdx.x; d < DD; d += 256) {
    xr[d]      = f2bf(h[d]);
    xr[DD + d] = f2bf(s[d] * inv);
  }
}

// -------- weight conversion with gate-interleave permutation: row' = u*4+g <- row g*768+u --------
__global__ void conv_w_perm(const float* __restrict__ w, unsigned short* __restrict__ o, int K)
{
  long i = (long)blockIdx.x * 256 + threadIdx.x;
  if (i >= (long)G4 * K) return;
  int row = (int)(i / K); int k = (int)(i - (long)row * K);
  int u = row >> 2, g = row & 3;
  o[i] = f2bf(w[((long)(g * DD + u)) * K + k]);
}

__global__ void conv_bias_perm(const float* __restrict__ bif, const float* __restrict__ bhf,
                               const float* __restrict__ bib, const float* __restrict__ bhb,
                               float* __restrict__ o)
{
  int n = blockIdx.x * 256 + threadIdx.x;
  if (n >= NB2) return;
  int d = n / G4, rr = n - d * G4, u = rr >> 2, g = rr & 3;
  int s = g * DD + u;
  o[n] = d ? (bib[s] + bhb[s]) : (bif[s] + bhf[s]);
}

// ---------------- GEMM: C[m,n] = sum_k A[m,k]*B[n,k] + bias[n], bf16 out ----------------
__global__ __launch_bounds__(256, 2)
void gemm_bt(const unsigned short* __restrict__ A, int lda,
             const unsigned short* __restrict__ B, int ldb,
             unsigned short* __restrict__ C, int ldc,
             const float* __restrict__ bias, int K)
{
  __shared__ unsigned short lA[128 * 32];
  __shared__ unsigned short lB[128 * 32];
  const int t = threadIdx.x;
  const int lane = t & 63;
  const int wv = t >> 6;
  const int wm = wv >> 1, wn = wv & 1;
  const int l15 = lane & 15, q = lane >> 4;
  const long m0 = (long)blockIdx.y * 128;
  const long n0 = (long)blockIdx.x * 128;
  const int rowS = t >> 2;
  const int kc = (((t & 3) ^ ((t >> 3) & 3))) * 8;         // swizzled source slot
  const int qsw = (q ^ ((l15 >> 1) & 3)) * 8;              // swizzled read slot
  const unsigned short* gA = A + (m0 + rowS) * lda + kc;
  const unsigned short* gB = B + (n0 + rowS) * ldb + kc;
  unsigned short* dA0 = lA + (wv << 9);
  unsigned short* dA1 = lA + 2048 + (wv << 9);
  unsigned short* dB0 = lB + (wv << 9);
  unsigned short* dB1 = lB + 2048 + (wv << 9);

  floatx4 acc[4][4];
  #pragma unroll
  for (int i = 0; i < 4; i++)
    #pragma unroll
    for (int j = 0; j < 4; j++)
      acc[i][j] = (floatx4){0.f, 0.f, 0.f, 0.f};

  const long a64 = (long)64 * lda;
  const long b64 = (long)64 * ldb;
  for (int kt = 0; kt < K; kt += 32) {
    gl_lds16(gA + kt,       dA0);
    gl_lds16(gA + a64 + kt, dA1);
    gl_lds16(gB + kt,       dB0);
    gl_lds16(gB + b64 + kt, dB1);
    __syncthreads();
    short8 af[4], bfr[4];
    #pragma unroll
    for (int i = 0; i < 4; i++)
      af[i] = *(const short8*)(lA + (wm * 64 + i * 16 + l15) * 32 + qsw);
    #pragma unroll
    for (int j = 0; j < 4; j++)
      bfr[j] = *(const short8*)(lB + (wn * 64 + j * 16 + l15) * 32 + qsw);
    #pragma unroll
    for (int i = 0; i < 4; i++)
      #pragma unroll
      for (int j = 0; j < 4; j++)
        acc[i][j] = __builtin_amdgcn_mfma_f32_16x16x32_bf16(af[i], bfr[j], acc[i][j], 0, 0, 0);
    __syncthreads();
  }

  #pragma unroll
  for (int i = 0; i < 4; i++) {
    #pragma unroll
    for (int j = 0; j < 4; j++) {
      const long mg = m0 + wm * 64 + i * 16 + q * 4;
      const long ng = n0 + wn * 64 + j * 16 + l15;
      const float bb = bias[ng];
      #pragma unroll
      for (int r = 0; r < 4; r++)
        C[(mg + r) * ldc + ng] = f2bf(acc[i][j][r] + bb);
    }
  }
}

// ---------------- persistent bidirectional LSTM recurrence ----------------
// 8 waves (2/SIMD). K-loop now a counted-vmcnt double-buffered pipeline (T3/T4):
// 12 k-tiles of K=64 (2 panels), compute tile kt from buf[kt&1] -> s_barrier ->
// stage tile kt+2 into buf[kt&1] -> vmcnt(4) (tile kt+1 done, kt+2 in flight;
// NEVER vmcnt(0) mid-loop) -> s_barrier. xg prefetch issued at k-loop head,
// retired by the first in-loop vmcnt(4). Grid barrier uses raw s_barriers with
// one explicit vmcnt(0) that drains only the 2 h-stores. sc1-coherent h path;
// transposed-MFMA zero-shuffle epilogue; XOR-swizzled LDS.
__global__ __launch_bounds__(512, 1)
void lstm_persist(const unsigned short* __restrict__ xg, int ldxg,
                  const unsigned short* __restrict__ whh,   // [2][3072][768] permuted
                  unsigned short* __restrict__ hbuf,        // [2][ndir][512][768]
                  unsigned short* __restrict__ outc,        // [16384][1536]
                  unsigned* bar,                            // 8 groups x 16 u32
                  int dir0, int ndir)
{
  __shared__ unsigned short bufA[16384];      // 2 bufs x 2 panels [128][32], swizzled
  __shared__ unsigned short bufB[16384];
  __shared__ unsigned short xgs[2][16384];    // double-buffered [128][128], swizzled
  __shared__ unsigned short hout[128 * 40];   // h staging, pad 40

  const int bid = blockIdx.x;
  const int xcd = bid & 7;
  const int idx = bid >> 3;
  int dm, k3;
  if (ndir == 2) { dm = idx & 7; k3 = idx >> 3; }
  else           { dm = idx & 3; k3 = idx >> 2; }
  const int ld  = (ndir == 2) ? (dm & 1) : 0;
  const int dir = dir0 + ld;
  const int mt  = (ndir == 2) ? (dm >> 1) : dm;
  const int nt  = k3 * 8 + xcd;
  const int m0 = mt * 128, n0 = nt * 128;
  const int u0 = n0 >> 2;
  unsigned* gbar = bar + dm * 16;
  const int nb24 = 24;

  const int t0 = threadIdx.x;
  const int lane = t0 & 63;
  const int wv = t0 >> 6;            // 0..7
  const int wm = wv >> 1;            // 0..3 : 32-row band
  const int wn = wv & 1;             // 0..1 : 64-col half
  const int l15 = lane & 15, q = lane >> 4;
  const long ldoff = (ndir == 2 && ld == 1) ? (long)G4 : 0;

  const unsigned short* Bdir = whh + (long)dir * G4 * DD;
  const int srow  = lane >> 2;                               // 0..15
  const int scolA = (((lane & 3) ^ ((lane >> 3) & 3))) * 8;  // staging source slot
  const int qsw   = (q ^ ((l15 >> 1) & 3)) * 8;              // fragment read slot
  const int xsw   = l15 << 3;                                // xgs read swizzle
  const int xsrc  = (((t0 & 15) ^ ((t0 >> 4) & 15))) * 8;    // xg staging source col

  const int rb = wv * 16 + srow;                             // staged row 0..127
  // s-invariant staging bases
  const unsigned short* wB  = Bdir + (long)(n0 + rb) * DD + scolA;
  const unsigned short* hA0 = hbuf + ((long)0 * ndir + ld) * ((long)SS * DD) + (long)(m0 + rb) * DD + scolA;
  const unsigned short* hA1 = hbuf + ((long)1 * ndir + ld) * ((long)SS * DD) + (long)(m0 + rb) * DD + scolA;
  unsigned short* dstA = bufA + wv * 512 + lane * 8;
  unsigned short* dstB = bufB + wv * 512 + lane * 8;

  float c_reg[2][4];
  #pragma unroll
  for (int i = 0; i < 2; i++)
    #pragma unroll
    for (int j = 0; j < 4; j++)
      c_reg[i][j] = 0.f;

  // prefetch step 0's xg tile into xgs[0]  (4 loads/wave)
  {
    const int tt0 = dir ? (BB - 1) : 0;
    const unsigned short* xrow = xg + ((long)tt0 * SS + m0) * ldxg + ldoff + n0;
    #pragma unroll
    for (int c = 0; c < 4; c++) {
      int row = c * 32 + (t0 >> 4);
      gl_lds16(xrow + (long)row * ldxg + xsrc,
               xgs[0] + c * 4096 + (t0 >> 4) * 128 + (t0 & 15) * 8);
    }
  }

  for (int s = 0; s < BB; s++) {
    const int tt = dir ? (BB - 1 - s) : s;
    const unsigned short* hA = (s & 1) ? hA1 : hA0;
    unsigned short* hw = hbuf + (((long)((s + 1) & 1)) * ndir + ld) * ((long)SS * DD);
    const unsigned short* xcur = xgs[s & 1];

    // ---- entry staging: tiles 0 and 1 (A first: longest latency), then xg for s+1 ----
    {
      gl_lds16_c(hA,        dstA);          // tile0 p0
      gl_lds16_c(hA + 32,   dstA + 4096);   // tile0 p1
      gl_lds16 (wB,         dstB);
      gl_lds16 (wB + 32,    dstB + 4096);
      gl_lds16_c(hA + 64,   dstA + 8192);   // tile1 p0
      gl_lds16_c(hA + 96,   dstA + 12288);  // tile1 p1
      gl_lds16 (wB + 64,    dstB + 8192);
      gl_lds16 (wB + 96,    dstB + 12288);
      if (s < BB - 1) {
        const int tn = dir ? (BB - 2 - s) : (s + 1);
        const unsigned short* xrow = xg + ((long)tn * SS + m0) * ldxg + ldoff + n0;
        unsigned short* xnxt = xgs[(s + 1) & 1];
        #pragma unroll
        for (int c = 0; c < 4; c++) {
          int row = c * 32 + (t0 >> 4);
          gl_lds16(xrow + (long)row * ldxg + xsrc,
                   xnxt + c * 4096 + (t0 >> 4) * 128 + (t0 & 15) * 8);
        }
      }
    }
    VMCNT(8);                               // tile0 done (+prev xg); tile1+xg may fly
    __builtin_amdgcn_s_barrier();

    floatx4 acc[2][4];
    #pragma unroll
    for (int i = 0; i < 2; i++)
      #pragma unroll
      for (int j = 0; j < 4; j++)
        acc[i][j] = (floatx4){0.f, 0.f, 0.f, 0.f};

    #pragma unroll
    for (int kt = 0; kt < 12; kt++) {
      const int cur = kt & 1;
      const unsigned short* pA = bufA + cur * 8192;
      const unsigned short* pB = bufB + cur * 8192;
      #pragma unroll
      for (int ks = 0; ks < 2; ks++) {
        short8 af[2], bfr[4];
        #pragma unroll
        for (int i = 0; i < 2; i++)
          af[i] = *(const short8*)(pA + ks * 4096 + (wm * 32 + i * 16 + l15) * 32 + qsw);
        #pragma unroll
        for (int j = 0; j < 4; j++)
          bfr[j] = *(const short8*)(pB + ks * 4096 + (wn * 64 + j * 16 + l15) * 32 + qsw);
        // TRANSPOSED: each lane's 4 acc regs = gates i,f,g,o of one unit
        #pragma unroll
        for (int i = 0; i < 2; i++)
          #pragma unroll
          for (int j = 0; j < 4; j++)
            acc[i][j] = __builtin_amdgcn_mfma_f32_16x16x32_bf16(bfr[j], af[i], acc[i][j], 0, 0, 0);
      }
      __builtin_amdgcn_s_barrier();         // all waves done reading buf[cur]
      if (kt < 10) {
        const long kb = (long)(kt + 2) * 64;
        unsigned short* dA = bufA + cur * 8192 + wv * 512 + lane * 8;
        unsigned short* dB = bufB + cur * 8192 + wv * 512 + lane * 8;
        gl_lds16_c(hA + kb,      dA);
        gl_lds16_c(hA + kb + 32, dA + 4096);
        gl_lds16 (wB + kb,      dB);
        gl_lds16 (wB + kb + 32, dB + 4096);
        VMCNT(4);                           // tile kt+1 done; kt+2 in flight
        __builtin_amdgcn_s_barrier();
      } else if (kt == 10) {
        VMCNT(0);                           // tile 11 done
        __builtin_amdgcn_s_barrier();
      }
    }

    // zero-shuffle gate epilogue
    #pragma unroll
    for (int i = 0; i < 2; i++) {
      const int mrow = wm * 32 + i * 16 + l15;
      const int xbase = mrow * 128;
      #pragma unroll
      for (int j = 0; j < 4; j++) {
        const int nb = wn * 64 + j * 16 + q * 4;
        shortx4 xv = *(const shortx4*)(xcur + xbase + (nb ^ xsw));
        float gi = acc[i][j][0] + bf2f((unsigned short)xv[0]);
        float gf = acc[i][j][1] + bf2f((unsigned short)xv[1]);
        float gg = acc[i][j][2] + bf2f((unsigned short)xv[2]);
        float go = acc[i][j][3] + bf2f((unsigned short)xv[3]);
        float c = sigf(gf) * c_reg[i][j] + sigf(gi) * tanhfast(gg);
        float h = sigf(go) * tanhfast(c);
        c_reg[i][j] = c;
        hout[mrow * 40 + (nb >> 2)] = f2bf(h);
      }
    }
    __syncthreads();
    // coalesced output: 4 threads/row, 8 shorts (16B) each
    {
      const int row = t0 >> 2;
      const int qq = t0 & 3;
      short8 v0 = *(const short8*)(hout + row * 40 + qq * 8);
      unsigned short* hwp = hw + (long)(m0 + row) * DD + u0 + qq * 8;
      unsigned short* op  = outc + ((long)tt * SS + m0 + row) * IN2 + dir * DD + u0 + qq * 8;
      store16_sc1(hwp, v0);
      *(short8*)op = v0;
    }
    if (s < BB - 1) {
      VMCNT(0);                             // only the 2 h-stores outstanding here
      __builtin_amdgcn_s_barrier();         // all waves' stores drained
      if (threadIdx.x == 0) {
        unsigned g = __hip_atomic_load(gbar + 1, __ATOMIC_RELAXED, __HIP_MEMORY_SCOPE_AGENT);
        unsigned a = __hip_atomic_fetch_add(gbar, 1u, __ATOMIC_RELAXED, __HIP_MEMORY_SCOPE_AGENT);
        if (a == (unsigned)(nb24 - 1)) {
          __hip_atomic_store(gbar, 0u, __ATOMIC_RELAXED, __HIP_MEMORY_SCOPE_AGENT);
          __hip_atomic_store(gbar + 1, g + 1u, __ATOMIC_RELEASE, __HIP_MEMORY_SCOPE_AGENT);
        } else {
          unsigned curv;
          do {
            __builtin_amdgcn_s_sleep(2);
            curv = __hip_atomic_load(gbar + 1, __ATOMIC_RELAXED, __HIP_MEMORY_SCOPE_AGENT);
          } while (curv == g);
        }
      }
      __builtin_amdgcn_s_barrier();
    }
  }
}

// ---------------- final linear [16384,1536](bf16) x [9,1536]^T ----------------
__global__ void final_linear(const unsigned short* __restrict__ xin, const float* __restrict__ w,
                             const float* __restrict__ b, float* __restrict__ out)
{
  __shared__ float red[NCLS * 256];
  int row = blockIdx.x;
  const unsigned short* x = xin + (long)row * IN2;
  float p[NCLS];
  #pragma unroll
  for (int c = 0; c < NCLS; c++) p[c] = 0.f;
  for (int k = threadIdx.x; k < IN2; k += 256) {
    float xv = bf2f(x[k]);
    #pragma unroll
    for (int c = 0; c < NCLS; c++) p[c] += xv * w[c * IN2 + k];
  }
  #pragma unroll
  for (int c = 0; c < NCLS; c++) red[c * 256 + threadIdx.x] = p[c];
  __syncthreads();
  for (int s = 128; s > 0; s >>= 1) {
    if (threadIdx.x < s) {
      #pragma unroll
      for (int c = 0; c < NCLS; c++)
        red[c * 256 + threadIdx.x] += red[c * 256 + threadIdx.x + s];
    }
    __syncthreads();
  }
  if (threadIdx.x < NCLS)
    out[(long)row * NCLS + threadIdx.x] = red[threadIdx.x * 256] + b[threadIdx.x];
}

extern "C" void kernel_launch(void* const* d_in, const int* in_sizes, int n_in,
                              void* d_out, int out_size, void* d_ws, size_t ws_size,
                              hipStream_t stream)
{
  const int*   batch  = (const int*)d_in[0];
  const float* hidden = (const float*)d_in[1];
  const float* w_ih_f = (const float*)d_in[2];
  const float* w_hh_f = (const float*)d_in[3];
  const float* b_ih_f = (const float*)d_in[4];
  const float* b_hh_f = (const float*)d_in[5];
  const float* w_ih_b = (const float*)d_in[6];
  const float* w_hh_b = (const float*)d_in[7];
  const float* b_ih_b = (const float*)d_in[8];
  const float* b_hh_b = (const float*)d_in[9];
  const float* lin_w  = (const float*)d_in[10];
  const float* lin_b  = (const float*)d_in[11];
  float* out = (float*)d_out;

  char* ws = (char*)d_ws;
  size_t off = 0;
  auto alloc = [&](size_t bytes) -> char* {
    char* p = ws + off;
    off += (bytes + 255) & ~(size_t)255;
    return p;
  };

  const size_t SZ_XG_A = (size_t)ROWS * NB2 * 2;      // 201.3 MB
  const size_t SZ_XG_B = (size_t)ROWS * G4  * 2;      // 100.7 MB
  const size_t SZ_XBF  = (size_t)ROWS * IN2 * 2;      //  50.3 MB
  const size_t SZ_W    = (size_t)G4 * IN2 * 2;        //   9.4 MB
  const size_t SZ_BIAS = (size_t)NB2 * 4;
  const size_t SZ_HBUF = (size_t)2 * 2 * SS * DD * 2; //   3.1 MB
  const size_t SZ_BAR  = 512;
  const size_t SZ_SUMS = (size_t)VOCAB * DD * 4 + (size_t)VOCAB * 4;

  const size_t NEED_C = SZ_XG_A + SZ_XBF + SZ_W + SZ_BIAS + SZ_HBUF + SZ_BAR + 8 * 256;
  const bool combined = ws_size >= NEED_C;

  const long nWIH = (long)G4 * IN2;
  const long nWHH = (long)G4 * DD;

  if (combined) {
    unsigned short* xg   = (unsigned short*)alloc(SZ_XG_A);
    unsigned short* xbf  = (unsigned short*)alloc(SZ_XBF);   // x input, later reused as outc
    unsigned short* wbuf = (unsigned short*)alloc(SZ_W);     // wih_f -> wih_b -> whh(both)
    float*          bias = (float*)alloc(SZ_BIAS);
    unsigned short* hbuf = (unsigned short*)alloc(SZ_HBUF);
    unsigned*       bar  = (unsigned*)alloc(SZ_BAR);
    float* sums   = (float*)xg;                              // overlay, consumed pre-xg-GEMM
    float* counts = sums + (size_t)VOCAB * DD;

    hipMemsetAsync(sums, 0, SZ_SUMS, stream);
    hipMemsetAsync(bar, 0, SZ_BAR, stream);
    seg_scatter<<<ROWS, 256, 0, stream>>>(batch, hidden, sums, counts);
    build_x<<<ROWS, 256, 0, stream>>>(batch, hidden, sums, counts, xbf);
    conv_bias_perm<<<(NB2 + 255) / 256, 256, 0, stream>>>(b_ih_f, b_hh_f, b_ih_b, b_hh_b, bias);

    for (int dir = 0; dir < 2; dir++) {
      conv_w_perm<<<(unsigned)((nWIH + 255) / 256), 256, 0, stream>>>(dir ? w_ih_b : w_ih_f, wbuf, IN2);
      dim3 grid(G4 / 128, ROWS / 128, 1);
      gemm_bt<<<grid, 256, 0, stream>>>(xbf, IN2, wbuf, IN2,
                                        xg + (size_t)dir * G4, NB2,
                                        bias + (size_t)dir * G4, IN2);
    }
    conv_w_perm<<<(unsigned)((nWHH + 255) / 256), 256, 0, stream>>>(w_hh_f, wbuf, DD);
    conv_w_perm<<<(unsigned)((nWHH + 255) / 256), 256, 0, stream>>>(w_hh_b, wbuf + (size_t)G4 * DD, DD);

    hipMemsetAsync(hbuf, 0, SZ_HBUF, stream);
    lstm_persist<<<192, 512, 0, stream>>>(xg, NB2, wbuf, hbuf, xbf, bar, 0, 2);
    final_linear<<<ROWS, 256, 0, stream>>>(xbf, lin_w, lin_b, out);
  } else {
    // direction-sequential (~223 MB, proven to fit)
    unsigned short* xg   = (unsigned short*)alloc(SZ_XG_B);
    unsigned short* xbf  = (unsigned short*)alloc(SZ_XBF);
    unsigned short* outc = (unsigned short*)alloc(SZ_XBF);
    unsigned short* wih  = (unsigned short*)alloc(SZ_W);
    unsigned short* whh  = (unsigned short*)alloc(SZ_W);
    float*          bias = (float*)alloc(SZ_BIAS);
    unsigned short* hbuf = (unsigned short*)alloc(SZ_HBUF);
    unsigned*       bar  = (unsigned*)alloc(SZ_BAR);
    float* sums   = (float*)xg;
    float* counts = sums + (size_t)VOCAB * DD;

    hipMemsetAsync(sums, 0, SZ_SUMS, stream);
    hipMemsetAsync(bar, 0, SZ_BAR, stream);
    seg_scatter<<<ROWS, 256, 0, stream>>>(batch, hidden, sums, counts);
    build_x<<<ROWS, 256, 0, stream>>>(batch, hidden, sums, counts, xbf);
    conv_bias_perm<<<(NB2 + 255) / 256, 256, 0, stream>>>(b_ih_f, b_hh_f, b_ih_b, b_hh_b, bias);
    conv_w_perm<<<(unsigned)((nWHH + 255) / 256), 256, 0, stream>>>(w_hh_f, whh, DD);
    conv_w_perm<<<(unsigned)((nWHH + 255) / 256), 256, 0, stream>>>(w_hh_b, whh + (size_t)G4 * DD, DD);

    for (int dir = 0; dir < 2; dir++) {
      conv_w_perm<<<(unsigned)((nWIH + 255) / 256), 256, 0, stream>>>(dir ? w_ih_b : w_ih_f, wih, IN2);
      {
        dim3 grid(G4 / 128, ROWS / 128, 1);
        gemm_bt<<<grid, 256, 0, stream>>>(xbf, IN2, wih, IN2, xg, G4,
                                          bias + (size_t)dir * G4, IN2);
      }
      hipMemsetAsync(hbuf, 0, SZ_HBUF, stream);
      lstm_persist<<<96, 512, 0, stream>>>(xg, G4, whh, hbuf, outc, bar, dir, 1);
    }
    final_linear<<<ROWS, 256, 0, stream>>>(outc, lin_w, lin_b, out);
  }
}